// Round 1
// baseline (127.709 us; speedup 1.0000x reference)
//
#include <hip/hip_runtime.h>

// Problem constants (fixed by the reference setup)
#define NB 8
#define KF 16
#define HGT 256
#define WID 256
#define HW (HGT * WID)          // 65536
#define NPIX (NB * HW)          // 524288
#define NPTS 100000
#define NCH 4

// ---------------------------------------------------------------------------
// Kernel 1: transpose ptclds (C,P) -> (P, C) float4 so each gather is one
// 16B L2 transaction instead of four 4B ones.
// ---------------------------------------------------------------------------
__global__ void ptclds_transpose_kernel(const float* __restrict__ pt,
                                        float4* __restrict__ ws) {
    int p = blockIdx.x * blockDim.x + threadIdx.x;
    if (p < NPTS) {
        ws[p] = make_float4(pt[p],
                            pt[NPTS + p],
                            pt[2 * NPTS + p],
                            pt[3 * NPTS + p]);
    }
}

// ---------------------------------------------------------------------------
// Kernel 2: one thread per pixel. Front-to-back compositing with exclusive
// cumprod transmittance. fragments are z-sorted: frag < 0 iff k >= cnt, so
// the first negative fragment ends the pixel.
// ---------------------------------------------------------------------------
template <bool PACKED>
__global__ __launch_bounds__(256) void composite_kernel(
    const int* __restrict__ frags,     // (N,K,H,W)
    const float* __restrict__ alphas,  // (N,K,H,W)
    const float* __restrict__ pt,      // (C,P)  (used when !PACKED)
    const float4* __restrict__ ws,     // (P,4)  (used when PACKED)
    const float* __restrict__ bg,      // (3,)
    float* __restrict__ out)           // (N,C,H,W)
{
    int i = blockIdx.x * blockDim.x + threadIdx.x;
    if (i >= NPIX) return;

    int n  = i >> 16;          // i / HW
    int hw = i & (HW - 1);     // i % HW

    long base = (long)n * KF * HW + hw;   // index of (n, k=0, h, w)

    float4 acc = make_float4(0.f, 0.f, 0.f, 0.f);

    int f0 = frags[base];
    if (f0 < 0) {
        // no nearest point -> background rgba (alpha = 1)
        acc = make_float4(bg[0], bg[1], bg[2], 1.0f);
    } else {
        float T = 1.0f;  // transmittance = prod_{j<k} (1 - a_j)
        int f = f0;
        #pragma unroll
        for (int k = 0; k < KF; ++k) {
            float a = alphas[base + (long)k * HW];
            float w = a * T;
            float4 feat;
            if (PACKED) {
                feat = ws[f];
            } else {
                feat = make_float4(pt[f], pt[NPTS + f],
                                   pt[2 * NPTS + f], pt[3 * NPTS + f]);
            }
            acc.x += w * feat.x;
            acc.y += w * feat.y;
            acc.z += w * feat.z;
            acc.w += w * feat.w;
            T *= (1.0f - a);
            if (k + 1 < KF) {
                f = frags[base + (long)(k + 1) * HW];
                if (f < 0) break;   // z-sorted: rest are invalid too
            }
        }
    }

    long ob = (long)n * NCH * HW + hw;
    out[ob]          = acc.x;
    out[ob + HW]     = acc.y;
    out[ob + 2 * HW] = acc.z;
    out[ob + 3 * HW] = acc.w;
}

extern "C" void kernel_launch(void* const* d_in, const int* in_sizes, int n_in,
                              void* d_out, int out_size, void* d_ws, size_t ws_size,
                              hipStream_t stream) {
    const int*   frags  = (const int*)d_in[0];    // fragments (N,K,H,W) int32
    const float* alphas = (const float*)d_in[1];  // alphas    (N,K,H,W) f32
    const float* pt     = (const float*)d_in[2];  // ptclds    (C,P)     f32
    const float* bg     = (const float*)d_in[3];  // background_color (3,) f32
    float* out = (float*)d_out;                   // (N,C,H,W) f32

    const bool packed = (ws_size >= (size_t)NPTS * sizeof(float4));

    if (packed) {
        float4* ws = (float4*)d_ws;
        ptclds_transpose_kernel<<<(NPTS + 255) / 256, 256, 0, stream>>>(pt, ws);
        composite_kernel<true><<<NPIX / 256, 256, 0, stream>>>(
            frags, alphas, pt, ws, bg, out);
    } else {
        composite_kernel<false><<<NPIX / 256, 256, 0, stream>>>(
            frags, alphas, pt, (const float4*)nullptr, bg, out);
    }
}

// Round 2
// 119.434 us; speedup vs baseline: 1.0693x; 1.0693x over previous
//
#include <hip/hip_runtime.h>

// Problem constants (fixed by the reference setup)
#define NB 8
#define KF 16
#define HGT 256
#define WID 256
#define HW (HGT * WID)          // 65536
#define NPIX (NB * HW)          // 524288
#define NPTS 100000
#define NCH 4

// ---------------------------------------------------------------------------
// Kernel 1: transpose ptclds (C,P) -> (P, 4) float4 so each gather is one
// 16B L2 transaction instead of four 4B ones. ptclds is 1.6 MB -> L2-resident.
// ---------------------------------------------------------------------------
__global__ void ptclds_transpose_kernel(const float* __restrict__ pt,
                                        float4* __restrict__ ws) {
    int p = blockIdx.x * blockDim.x + threadIdx.x;
    if (p < NPTS) {
        ws[p] = make_float4(pt[p],
                            pt[NPTS + p],
                            pt[2 * NPTS + p],
                            pt[3 * NPTS + p]);
    }
}

// ---------------------------------------------------------------------------
// Kernel 2: branchless compositing, 2 pixels per thread.
// No early break -> all 16 frag loads are independent and get issued up-front
// (full MLP); invalid slots contribute weight 0 and gather from index 0
// (single broadcast cacheline). int2/float2 loads keep 8B/lane coalescing.
// ---------------------------------------------------------------------------
template <bool PACKED>
__global__ __launch_bounds__(256) void composite_kernel(
    const int* __restrict__ frags,     // (N,K,H,W)
    const float* __restrict__ alphas,  // (N,K,H,W)
    const float* __restrict__ pt,      // (C,P)  (used when !PACKED)
    const float4* __restrict__ ws,     // (P,4)  (used when PACKED)
    const float* __restrict__ bg,      // (3,)
    float* __restrict__ out)           // (N,C,H,W)
{
    int t = blockIdx.x * blockDim.x + threadIdx.x;
    if (t >= NPIX / 2) return;

    int n  = t >> 15;                 // t / (HW/2)
    int hw = (t & 32767) << 1;        // 2 consecutive pixels

    long base = (long)n * KF * HW + hw;

    // Stage all fragment indices first: 16 independent coalesced int2 loads.
    int2 f[KF];
    #pragma unroll
    for (int k = 0; k < KF; ++k)
        f[k] = *reinterpret_cast<const int2*>(&frags[base + (long)k * HW]);

    float bg0 = bg[0], bg1 = bg[1], bg2 = bg[2];

    float4 acc0 = make_float4(0.f, 0.f, 0.f, 0.f);
    float4 acc1 = make_float4(0.f, 0.f, 0.f, 0.f);
    float T0 = 1.0f, T1 = 1.0f;

    #pragma unroll
    for (int k = 0; k < KF; ++k) {
        float2 a = *reinterpret_cast<const float2*>(&alphas[base + (long)k * HW]);
        const bool v0 = f[k].x >= 0;
        const bool v1 = f[k].y >= 0;
        const int i0 = v0 ? f[k].x : 0;
        const int i1 = v1 ? f[k].y : 0;
        float4 g0, g1;
        if (PACKED) {
            g0 = ws[i0];
            g1 = ws[i1];
        } else {
            g0 = make_float4(pt[i0], pt[NPTS + i0], pt[2*NPTS + i0], pt[3*NPTS + i0]);
            g1 = make_float4(pt[i1], pt[NPTS + i1], pt[2*NPTS + i1], pt[3*NPTS + i1]);
        }
        const float a0 = v0 ? a.x : 0.f;
        const float a1 = v1 ? a.y : 0.f;
        const float w0 = a0 * T0;
        const float w1 = a1 * T1;
        acc0.x += w0 * g0.x;  acc0.y += w0 * g0.y;
        acc0.z += w0 * g0.z;  acc0.w += w0 * g0.w;
        acc1.x += w1 * g1.x;  acc1.y += w1 * g1.y;
        acc1.z += w1 * g1.z;  acc1.w += w1 * g1.w;
        T0 *= (1.0f - a0);
        T1 *= (1.0f - a1);
    }

    // Background fill where no nearest point exists.
    if (f[0].x < 0) acc0 = make_float4(bg0, bg1, bg2, 1.0f);
    if (f[0].y < 0) acc1 = make_float4(bg0, bg1, bg2, 1.0f);

    long ob = (long)n * NCH * HW + hw;
    *reinterpret_cast<float2*>(&out[ob])          = make_float2(acc0.x, acc1.x);
    *reinterpret_cast<float2*>(&out[ob + HW])     = make_float2(acc0.y, acc1.y);
    *reinterpret_cast<float2*>(&out[ob + 2 * HW]) = make_float2(acc0.z, acc1.z);
    *reinterpret_cast<float2*>(&out[ob + 3 * HW]) = make_float2(acc0.w, acc1.w);
}

extern "C" void kernel_launch(void* const* d_in, const int* in_sizes, int n_in,
                              void* d_out, int out_size, void* d_ws, size_t ws_size,
                              hipStream_t stream) {
    const int*   frags  = (const int*)d_in[0];    // fragments (N,K,H,W) int32
    const float* alphas = (const float*)d_in[1];  // alphas    (N,K,H,W) f32
    const float* pt     = (const float*)d_in[2];  // ptclds    (C,P)     f32
    const float* bg     = (const float*)d_in[3];  // background_color (3,) f32
    float* out = (float*)d_out;                   // (N,C,H,W) f32

    const bool packed = (ws_size >= (size_t)NPTS * sizeof(float4));

    if (packed) {
        float4* ws = (float4*)d_ws;
        ptclds_transpose_kernel<<<(NPTS + 255) / 256, 256, 0, stream>>>(pt, ws);
        composite_kernel<true><<<(NPIX / 2) / 256, 256, 0, stream>>>(
            frags, alphas, pt, ws, bg, out);
    } else {
        composite_kernel<false><<<(NPIX / 2) / 256, 256, 0, stream>>>(
            frags, alphas, pt, (const float4*)nullptr, bg, out);
    }
}

// Round 4
// 115.886 us; speedup vs baseline: 1.1020x; 1.0306x over previous
//
#include <hip/hip_runtime.h>

// Problem constants (fixed by the reference setup)
#define NB 8
#define KF 16
#define HGT 256
#define WID 256
#define HW (HGT * WID)          // 65536
#define NPIX (NB * HW)          // 524288
#define NPTS 100000
#define NCH 4

// ---------------------------------------------------------------------------
// Kernel 1: transpose ptclds (C,P) -> (P, 4) float4 so each gather is one
// 16B L2 transaction instead of four 4B ones. ptclds is 1.6 MB -> L2-resident.
// ---------------------------------------------------------------------------
__global__ void ptclds_transpose_kernel(const float* __restrict__ pt,
                                        float4* __restrict__ ws) {
    int p = blockIdx.x * blockDim.x + threadIdx.x;
    if (p < NPTS) {
        ws[p] = make_float4(pt[p],
                            pt[NPTS + p],
                            pt[2 * NPTS + p],
                            pt[3 * NPTS + p]);
    }
}

// ---------------------------------------------------------------------------
// Kernel 2: branchless compositing, 1 pixel per thread (2048 blocks -> up to
// 8 blocks/CU of TLP). All 16 frag loads + 16 alpha loads + 16 gathers are
// independent -> deep MLP per thread. NO nontemporal builtins: nt stores
// race with the harness's 0xAA poison fill across graph replays (R3 lesson).
// ---------------------------------------------------------------------------
template <bool PACKED>
__global__ __launch_bounds__(256, 6) void composite_kernel(
    const int* __restrict__ frags,     // (N,K,H,W)
    const float* __restrict__ alphas,  // (N,K,H,W)
    const float* __restrict__ pt,      // (C,P)  (used when !PACKED)
    const float4* __restrict__ ws,     // (P,4)  (used when PACKED)
    const float* __restrict__ bg,      // (3,)
    float* __restrict__ out)           // (N,C,H,W)
{
    int i = blockIdx.x * blockDim.x + threadIdx.x;
    if (i >= NPIX) return;

    int n  = i >> 16;          // i / HW
    int hw = i & (HW - 1);     // i % HW

    long base = (long)n * KF * HW + hw;

    // Stage all fragment indices and alphas: 32 independent coalesced loads.
    int f[KF];
    float a[KF];
    #pragma unroll
    for (int k = 0; k < KF; ++k)
        f[k] = frags[base + (long)k * HW];
    #pragma unroll
    for (int k = 0; k < KF; ++k)
        a[k] = alphas[base + (long)k * HW];

    float4 acc = make_float4(0.f, 0.f, 0.f, 0.f);
    float T = 1.0f;

    #pragma unroll
    for (int k = 0; k < KF; ++k) {
        const bool v = f[k] >= 0;
        const int idx = v ? f[k] : 0;   // invalid -> broadcast line 0
        float4 g;
        if (PACKED) {
            g = ws[idx];
        } else {
            g = make_float4(pt[idx], pt[NPTS + idx],
                            pt[2 * NPTS + idx], pt[3 * NPTS + idx]);
        }
        const float av = v ? a[k] : 0.f;
        const float w = av * T;
        acc.x += w * g.x;
        acc.y += w * g.y;
        acc.z += w * g.z;
        acc.w += w * g.w;
        T *= (1.0f - av);
    }

    // Background fill where no nearest point exists.
    if (f[0] < 0) acc = make_float4(bg[0], bg[1], bg[2], 1.0f);

    long ob = (long)n * NCH * HW + hw;
    out[ob]          = acc.x;
    out[ob + HW]     = acc.y;
    out[ob + 2 * HW] = acc.z;
    out[ob + 3 * HW] = acc.w;
}

extern "C" void kernel_launch(void* const* d_in, const int* in_sizes, int n_in,
                              void* d_out, int out_size, void* d_ws, size_t ws_size,
                              hipStream_t stream) {
    const int*   frags  = (const int*)d_in[0];    // fragments (N,K,H,W) int32
    const float* alphas = (const float*)d_in[1];  // alphas    (N,K,H,W) f32
    const float* pt     = (const float*)d_in[2];  // ptclds    (C,P)     f32
    const float* bg     = (const float*)d_in[3];  // background_color (3,) f32
    float* out = (float*)d_out;                   // (N,C,H,W) f32

    const bool packed = (ws_size >= (size_t)NPTS * sizeof(float4));

    if (packed) {
        float4* ws = (float4*)d_ws;
        ptclds_transpose_kernel<<<(NPTS + 255) / 256, 256, 0, stream>>>(pt, ws);
        composite_kernel<true><<<NPIX / 256, 256, 0, stream>>>(
            frags, alphas, pt, ws, bg, out);
    } else {
        composite_kernel<false><<<NPIX / 256, 256, 0, stream>>>(
            frags, alphas, pt, (const float4*)nullptr, bg, out);
    }
}